// Round 10
// baseline (1982.350 us; speedup 1.0000x reference)
//
#include <hip/hip_runtime.h>
#include <hip/hip_bf16.h>
#include <math.h>

typedef float v2f __attribute__((ext_vector_type(2)));

// ---------------- problem constants ----------------
#define BIMG   4
#define CIN    512
#define MID    512
#define HF     50
#define WF     50
#define PIX    2500          // HF*WF
#define MTOT   10000         // BIMG*PIX
#define ANC    9
#define NLOC   22500         // PIX*ANC
#define NPRE   3000
#define NPOST  300
#define WORDS  47            // ceil(3000/64)
#define ROWPAD 3008
#define WSTRIDE 48           // padded words per NMS row
#define CAP    8192          // candidate capacity per image

// d_out layout (floats): rois, rois_idx, anchors, loc, bf_pred
#define ROIS_OFF 0
#define IDX_OFF  4800
#define ANC_OFF  6000
#define LOC_OFF  96000
#define BF_OFF   456000

// ws layout (byte offsets).
#define WS_WT     0UL                      // 4608*512 f32 = 9,437,184 B; rawp0..2 alias after conv3x3
#define WS_W1T    9437184UL                // 512*64 f32     =   131,072 B
#define WS_FEAT   9568256UL                // 10000*512 f32  = 20,480,000 B (K-split partial 0)
#define WS_SCORE  30048256UL               // 90000 u64 keys =    720,000 B
#define WS_BOXD   30768256UL               // 90000*4 f64    =  2,880,000 B
#define WS_SBD    33648256UL               // 4*3000*4 f64   =    384,000 B
#define WS_M      34032256UL               // 4*3008*48 u64  =  4,620,288 B (rawp3 aliases before nmsmask)
#define WS_CAND   38652544UL               // 4*8192 u32     =    131,072 B
#define WS_CNT    38783616UL               // 4 u32
#define WS_PART1  38786048UL               // partial 1
#define WS_PART2  59266048UL               // partial 2
#define WS_PART3  79746048UL               // partial 3
#define WS_NEED2  59266048UL
#define WS_NEED4  100226048UL
#define RAWP_SZ   2560000UL                // 10000*64 f32

// ---------------- kernel 0: weight prep ----------------
// Wt[(tap*512 + c)*512 + co] = conv_w[co][c][tap]
__global__ __launch_bounds__(256) void prep_kernel(
    const float* __restrict__ conv_w, const float* __restrict__ loc_w,
    const float* __restrict__ bf_w, float* __restrict__ Wt, float* __restrict__ W1t) {
  int o = blockIdx.x * 256 + threadIdx.x;
  if (o < 4608 * 512) {
    int co  = o & 511;
    int k   = o >> 9;          // tap*512 + c
    int c   = k & 511;
    int tap = k >> 9;
    Wt[o] = conv_w[(co * 512 + c) * 9 + tap];
  } else {
    int o2 = o - 4608 * 512;
    if (o2 < 512 * 64) {
      int co = o2 & 63;
      int c  = o2 >> 6;
      float v = 0.0f;
      if (co < 36)      v = loc_w[co * 512 + c];
      else if (co < 54) v = bf_w[(co - 36) * 512 + c];
      W1t[o2] = v;
    }
  }
}

// ---------------- kernel 1: 3x3 conv, K-split partials, pk-fma inner ----------------
// M=128, 16 cols/wave (scalar-B), packed f32 FMA over the pixel pair
// (v_pk_fma_f32: same component ops/order as before -> bit-identical),
// f64 fold every 2 kb. grid.z splits K into nz chunks -> f32 partials.
__device__ __forceinline__ void stage_load(
    int kb, int sg, bool in0, bool in1,
    int y0, int x0, int y1, int x1,
    const float* __restrict__ ib0, const float* __restrict__ ib1, float av[8]) {
  int tap = kb >> 5;
  int c0  = (kb & 31) << 4;
  int t3  = tap / 3;
  int dy  = t3 - 1;
  int dx  = tap - t3 * 3 - 1;
  int iy0 = y0 + dy, ix0 = x0 + dx;
  int iy1 = y1 + dy, ix1 = x1 + dx;
  bool ok0 = in0 && ((unsigned)iy0 < (unsigned)HF) && ((unsigned)ix0 < (unsigned)WF);
  bool ok1 = in1 && ((unsigned)iy1 < (unsigned)HF) && ((unsigned)ix1 < (unsigned)WF);
  int base = (c0 + sg * 4) * PIX;
  int o0 = iy0 * WF + ix0;
  int o1 = iy1 * WF + ix1;
#pragma unroll
  for (int j = 0; j < 4; ++j) {
    av[2 * j]     = ok0 ? ib0[base + j * PIX + o0] : 0.0f;
    av[2 * j + 1] = ok1 ? ib1[base + j * PIX + o1] : 0.0f;
  }
}

__global__ __launch_bounds__(256, 3) void conv3x3_kernel(
    const float* __restrict__ in, const float* __restrict__ Wt,
    float* __restrict__ part0, float* __restrict__ part1,
    float* __restrict__ part2, float* __restrict__ part3) {
  __shared__ float As[2][16][128];
  const int tid = threadIdx.x;
  const int q0 = blockIdx.x * 128;
  const int lane = tid & 63;
  const int wv = tid >> 6;
  const int col0 = __builtin_amdgcn_readfirstlane(blockIdx.y * 64 + wv * 16);
  const int half = 288 / gridDim.z;
  const int kb0 = blockIdx.z * half;
  float* __restrict__ dst = (blockIdx.z == 0) ? part0 :
                            (blockIdx.z == 1) ? part1 :
                            (blockIdx.z == 2) ? part2 : part3;

  const int sg = tid >> 6;
  const int sp = tid & 63;
  int qs0 = q0 + 2 * sp, qs1 = qs0 + 1;
  bool in0 = qs0 < MTOT, in1 = qs1 < MTOT;
  int t0 = in0 ? qs0 : 0, t1 = in1 ? qs1 : 0;
  int b0i = t0 / PIX, r0 = t0 - b0i * PIX, y0 = r0 / WF, x0 = r0 - y0 * WF;
  int b1i = t1 / PIX, r1 = t1 - b1i * PIX, y1 = r1 / WF, x1 = r1 - y1 * WF;
  const float* ib0 = in + (size_t)b0i * (CIN * PIX);
  const float* ib1 = in + (size_t)b1i * (CIN * PIX);

  double acc[2][16];
  v2f accf2[16];
  const v2f vzero = {0.0f, 0.0f};
#pragma unroll
  for (int c = 0; c < 16; ++c) {
    acc[0][c] = 0.0; acc[1][c] = 0.0; accf2[c] = vzero;
  }

  // prologue: stage kb0 into buffer 0
  {
    float av[8];
    stage_load(kb0, sg, in0, in1, y0, x0, y1, x1, ib0, ib1, av);
#pragma unroll
    for (int j = 0; j < 4; ++j)
      *(float2*)&As[0][sg * 4 + j][2 * sp] = make_float2(av[2 * j], av[2 * j + 1]);
  }
  __syncthreads();

  for (int kbl = 0; kbl < half; ++kbl) {
    int kb = kb0 + kbl;
    int cur = kbl & 1;
    float av[8];
    bool has_next = (kbl + 1 < half);
    if (has_next)
      stage_load(kb + 1, sg, in0, in1, y0, x0, y1, x1, ib0, ib1, av);

    const float* __restrict__ Bw = Wt + (size_t)(kb * 16) * 512 + col0;
#pragma unroll
    for (int kg = 0; kg < 4; ++kg) {
#pragma unroll
      for (int kq = 0; kq < 4; ++kq) {
        int kk = kg * 4 + kq;
        const float* __restrict__ br = Bw + (size_t)kk * 512;
        v2f a2 = *(const v2f*)&As[cur][kk][2 * lane];
#pragma unroll
        for (int c = 0; c < 16; ++c) {
          float bv = br[c];            // wave-uniform -> s_load
          v2f b2 = {bv, bv};
          accf2[c] = __builtin_elementwise_fma(a2, b2, accf2[c]);  // v_pk_fma_f32
        }
      }
    }
    if (kbl & 1) {                 // fold every 2 kb (32-MAC f32 chains)
#pragma unroll
      for (int c = 0; c < 16; ++c) {
        acc[0][c] += (double)accf2[c][0];
        acc[1][c] += (double)accf2[c][1];
        accf2[c] = vzero;
      }
    }
    if (has_next) {
      int nxt = cur ^ 1;
#pragma unroll
      for (int j = 0; j < 4; ++j)
        *(float2*)&As[nxt][sg * 4 + j][2 * sp] = make_float2(av[2 * j], av[2 * j + 1]);
    }
    __syncthreads();
  }

#pragma unroll
  for (int p = 0; p < 2; ++p) {
    int q = q0 + 2 * lane + p;
    if (q < MTOT) {
      float o[16];
#pragma unroll
      for (int c = 0; c < 16; ++c) o[c] = (float)acc[p][c];
      float* fp = &dst[(size_t)q * 512 + col0];
#pragma unroll
      for (int g = 0; g < 4; ++g)
        *(float4*)&fp[g * 4] = make_float4(o[g*4], o[g*4+1], o[g*4+2], o[g*4+3]);
    }
  }
}

// ---------------- kernel 2: 1x1 heads, K-split x4 + 64-pixel tile ----------------
// grid (157, 4): block (x,y) computes f32 partial rawp_y[q0..q0+64][64 cols]
// over feat channels [y*128, y*128+128). Staging computes
// relu(conv_b + sum of conv3x3 partials) inline (identical per-element math).
__global__ __launch_bounds__(256) void conv1x1_kernel(
    const float* __restrict__ p0, const float* __restrict__ p1,
    const float* __restrict__ p2, const float* __restrict__ p3, int nz,
    const float* __restrict__ convb, const float* __restrict__ W1t,
    float* __restrict__ rawp0, float* __restrict__ rawp1,
    float* __restrict__ rawp2, float* __restrict__ rawp3) {
  __shared__ float As[16][64];
  const int tid = threadIdx.x;
  const int q0 = blockIdx.x * 64;
  const int by = blockIdx.y;
  const int lane = tid & 63;
  const int wv = tid >> 6;
  const int col0 = __builtin_amdgcn_readfirstlane(wv * 16);   // 4 waves x 16 = 64 cols
  float* __restrict__ rp = (by == 0) ? rawp0 : (by == 1) ? rawp1 :
                           (by == 2) ? rawp2 : rawp3;

  const int sg = tid >> 6;
  const int sp = tid & 63;
  const int qs = q0 + sp;
  const bool okL = qs < MTOT;

  double acc[16];
  float accf[16];
#pragma unroll
  for (int c = 0; c < 16; ++c) { acc[c] = 0.0; accf[c] = 0.0f; }

  for (int kbl = 0; kbl < 8; ++kbl) {
    int kb = by * 8 + kbl;
    int c0 = kb * 16;
    float fv[4] = {0.0f, 0.0f, 0.0f, 0.0f};
    if (okL) {
      const size_t base = (size_t)qs * 512 + c0 + sg * 4;
      double s[4];
      float4 a0 = *(const float4*)&p0[base];
      s[0] = (double)a0.x; s[1] = (double)a0.y; s[2] = (double)a0.z; s[3] = (double)a0.w;
      if (nz > 1) {
        float4 b0 = *(const float4*)&p1[base];
        s[0] += (double)b0.x; s[1] += (double)b0.y; s[2] += (double)b0.z; s[3] += (double)b0.w;
      }
      if (nz > 2) {
        float4 c0v = *(const float4*)&p2[base];
        s[0] += (double)c0v.x; s[1] += (double)c0v.y; s[2] += (double)c0v.z; s[3] += (double)c0v.w;
        float4 d0 = *(const float4*)&p3[base];
        s[0] += (double)d0.x; s[1] += (double)d0.y; s[2] += (double)d0.z; s[3] += (double)d0.w;
      }
      float4 bsv = *(const float4*)&convb[c0 + sg * 4];
      fv[0] = (float)fmax(s[0] + (double)bsv.x, 0.0);
      fv[1] = (float)fmax(s[1] + (double)bsv.y, 0.0);
      fv[2] = (float)fmax(s[2] + (double)bsv.z, 0.0);
      fv[3] = (float)fmax(s[3] + (double)bsv.w, 0.0);
    }
    __syncthreads();
#pragma unroll
    for (int j = 0; j < 4; ++j) As[sg * 4 + j][sp] = fv[j];
    __syncthreads();

    const float* __restrict__ Bw = W1t + (size_t)c0 * 64 + col0;
#pragma unroll
    for (int kk = 0; kk < 16; ++kk) {
      const float* __restrict__ br = Bw + (size_t)kk * 64;
      float a = As[kk][lane];
#pragma unroll
      for (int c = 0; c < 16; ++c)
        accf[c] = fmaf(a, br[c], accf[c]);
    }
    if (kbl & 1) {                 // fold every 2 kb (32-MAC chains)
#pragma unroll
      for (int c = 0; c < 16; ++c) {
        acc[c] += (double)accf[c];
        accf[c] = 0.0f;
      }
    }
  }

  int q = q0 + lane;
  if (q < MTOT) {
    float o[16];
#pragma unroll
    for (int c = 0; c < 16; ++c) o[c] = (float)acc[c];
    float* fp = &rp[(size_t)q * 64 + col0];
#pragma unroll
    for (int g = 0; g < 4; ++g)
      *(float4*)&fp[g * 4] = make_float4(o[g*4], o[g*4+1], o[g*4+2], o[g*4+3]);
  }
}

// ---------------- kernel 3: epilogue — sum rawp + head bias (f64), softmax/decode/clip, u64 keys ----------------
__global__ __launch_bounds__(256) void epilogue_kernel(
    const float* __restrict__ r0, const float* __restrict__ r1,
    const float* __restrict__ r2, const float* __restrict__ r3,
    const float* __restrict__ locb, const float* __restrict__ bfb,
    float* __restrict__ d_out, double* __restrict__ boxd,
    unsigned long long* __restrict__ ukey,
    const int* __restrict__ imh, const int* __restrict__ imw) {
  int idx = blockIdx.x * 256 + threadIdx.x;
  if (idx >= BIMG * NLOC) return;
  int b = idx / NLOC;
  int i = idx - b * NLOC;
  int p = i / ANC;
  int a = i - p * ANC;
  int y = p / WF;
  int x = p - y * WF;
  int q = b * PIX + p;
  const size_t rb = (size_t)q * 64;

  // loc: co = a*4 .. a*4+3, bias = locb
  float4 A0 = *(const float4*)&r0[rb + a * 4];
  float4 A1 = *(const float4*)&r1[rb + a * 4];
  float4 A2 = *(const float4*)&r2[rb + a * 4];
  float4 A3 = *(const float4*)&r3[rb + a * 4];
  double l0d = (((double)A0.x + (double)A1.x) + (double)A2.x) + (double)A3.x + (double)locb[a * 4 + 0];
  double l1d = (((double)A0.y + (double)A1.y) + (double)A2.y) + (double)A3.y + (double)locb[a * 4 + 1];
  double l2d = (((double)A0.z + (double)A1.z) + (double)A2.z) + (double)A3.z + (double)locb[a * 4 + 2];
  double l3d = (((double)A0.w + (double)A1.w) + (double)A2.w) + (double)A3.w + (double)locb[a * 4 + 3];
  *(float4*)&d_out[LOC_OFF + (size_t)idx * 4] =
      make_float4((float)l0d, (float)l1d, (float)l2d, (float)l3d);

  // logits: co = 36+2a, 37+2a, bias = bfb
  float2 G0 = *(const float2*)&r0[rb + 36 + a * 2];
  float2 G1 = *(const float2*)&r1[rb + 36 + a * 2];
  float2 G2 = *(const float2*)&r2[rb + 36 + a * 2];
  float2 G3 = *(const float2*)&r3[rb + 36 + a * 2];
  double g0 = (((double)G0.x + (double)G1.x) + (double)G2.x) + (double)G3.x + (double)bfb[a * 2 + 0];
  double g1 = (((double)G0.y + (double)G1.y) + (double)G2.y) + (double)G3.y + (double)bfb[a * 2 + 1];
  double m  = fmax(g0, g1);
  double e0 = exp(g0 - m), e1 = exp(g1 - m);
  double s  = e0 + e1;
  double p0 = e0 / s, p1 = e1 / s;
  *(float2*)&d_out[BF_OFF + (size_t)idx * 2] = make_float2((float)p0, (float)p1);

  // anchor (f64)
  int ridx = a / 3, sidx = a - ridx * 3;
  double ratio = (ridx == 0) ? 0.5 : ((ridx == 1) ? 1.0 : 2.0);
  double scale = (sidx == 0) ? 8.0 : ((sidx == 1) ? 16.0 : 32.0);
  double hs = 16.0 * scale * sqrt(ratio);
  double ws = 16.0 * scale * sqrt(1.0 / ratio);
  double sy = (double)(y * 16), sx = (double)(x * 16);
  double a0 = sy + (8.0 - hs * 0.5);
  double a1 = sx + (8.0 - ws * 0.5);
  double a2 = sy + (8.0 + hs * 0.5);
  double a3 = sx + (8.0 + ws * 0.5);
  if (b == 0) {
    *(float4*)&d_out[ANC_OFF + (size_t)i * 4] =
        make_float4((float)a0, (float)a1, (float)a2, (float)a3);
  }

  // decode + clip (f64)
  double ah = a2 - a0, aw = a3 - a1;
  double acy = a0 + 0.5 * ah, acx = a1 + 0.5 * aw;
  double cy = l0d * ah + acy;
  double cx = l1d * aw + acx;
  double hh = exp(l2d) * ah;
  double ww = exp(l3d) * aw;
  double ihf = (double)imh[0], iwf = (double)imw[0];
  double b0 = fmin(fmax(cy - 0.5 * hh, 0.0), ihf);
  double b1 = fmin(fmax(cx - 0.5 * ww, 0.0), iwf);
  double b2 = fmin(fmax(cy + 0.5 * hh, 0.0), ihf);
  double b3 = fmin(fmax(cx + 0.5 * ww, 0.0), iwf);
  double* bp = &boxd[(size_t)idx * 4];
  bp[0] = b0; bp[1] = b1; bp[2] = b2; bp[3] = b3;

  bool valid = (b2 - b0 >= 16.0) && (b3 - b1 >= 16.0);
  double d = valid ? (g1 - g0) : -INFINITY;
  long long bits = __double_as_longlong(d);
  unsigned long long u = (bits < 0)
      ? ~(unsigned long long)bits
      : ((unsigned long long)bits | 0x8000000000000000ull);
  ukey[idx] = ~u;   // smaller key = better rank
}

// ---------------- kernel 4a: histogram -> threshold bin + candidate compaction ----------------
__global__ __launch_bounds__(1024) void thresh_kernel(
    const unsigned long long* __restrict__ ukey,
    unsigned* __restrict__ ccnt, unsigned* __restrict__ cand) {
  __shared__ unsigned hist[16384];
  __shared__ unsigned csum[1024];
  __shared__ unsigned sT, scnt;
  int b = blockIdx.x;
  int tid = threadIdx.x;
  for (int i = tid; i < 16384; i += 1024) hist[i] = 0;
  if (tid == 0) scnt = 0;
  __syncthreads();
  for (int j = tid; j < NLOC; j += 1024)
    atomicAdd(&hist[(unsigned)(ukey[(size_t)b * NLOC + j] >> 50)], 1u);
  __syncthreads();
  unsigned s = 0;
#pragma unroll
  for (int k = 0; k < 16; ++k) s += hist[tid * 16 + k];
  csum[tid] = s;
  __syncthreads();
  if (tid == 0) {
    unsigned cum = 0;
    int T = 16383;
    for (int c = 0; c < 1024; ++c) {
      if (cum + csum[c] >= NPRE) {
        unsigned cc = cum;
        for (int k = 0; k < 16; ++k) {
          cc += hist[c * 16 + k];
          if (cc >= NPRE) { T = c * 16 + k; break; }
        }
        break;
      }
      cum += csum[c];
    }
    sT = (unsigned)T;
  }
  __syncthreads();
  unsigned T = sT;
  for (int j = tid; j < NLOC; j += 1024) {
    if ((unsigned)(ukey[(size_t)b * NLOC + j] >> 50) <= T) {
      unsigned slot = atomicAdd(&scnt, 1u);
      if (slot < CAP) cand[(size_t)b * CAP + slot] = (unsigned)j;
    }
  }
  __syncthreads();
  if (tid == 0) ccnt[b] = scnt;
}

// ---------------- kernel 4b: exact rank among candidates -> sb ----------------
__global__ __launch_bounds__(256) void rank_kernel(
    const unsigned long long* __restrict__ ukey, const unsigned* __restrict__ ccnt,
    const unsigned* __restrict__ cand, const double* __restrict__ boxd,
    double* __restrict__ sbd) {
  __shared__ unsigned long long kt[256];
  __shared__ unsigned it[256];
  int b = blockIdx.y;
  int C = (int)min(ccnt[b], (unsigned)CAP);
  int s = blockIdx.x * 256 + threadIdx.x;
  bool act = s < C;
  unsigned myi = act ? cand[(size_t)b * CAP + s] : 0xFFFFFFFFu;
  unsigned long long ki = act ? ukey[(size_t)b * NLOC + myi] : ~0ull;
  int cnt = 0;
  int ntile = (C + 255) >> 8;
  for (int t = 0; t < ntile; ++t) {
    int j = t * 256 + threadIdx.x;
    unsigned ji = (j < C) ? cand[(size_t)b * CAP + j] : 0xFFFFFFFFu;
    kt[threadIdx.x] = (j < C) ? ukey[(size_t)b * NLOC + ji] : ~0ull;
    it[threadIdx.x] = ji;
    __syncthreads();
#pragma unroll 8
    for (int jj = 0; jj < 256; ++jj) {
      unsigned long long kj = kt[jj];
      unsigned jidx = it[jj];
      cnt += ((kj < ki) || (kj == ki && jidx < myi)) ? 1 : 0;
    }
    __syncthreads();
  }
  if (act && cnt < NPRE) {
    const double* bx = &boxd[((size_t)b * NLOC + myi) * 4];
    double* dp = &sbd[((size_t)b * NPRE + cnt) * 4];
    dp[0] = bx[0]; dp[1] = bx[1]; dp[2] = bx[2]; dp[3] = bx[3];
  }
}

// ---------------- kernel 5: NMS suppression bitmask matrix (f64 IoU) ----------------
__global__ __launch_bounds__(64) void nmsmask_kernel(
    const double* __restrict__ sbd, unsigned long long* __restrict__ M) {
  __shared__ double cb[64][4];
  int b = blockIdx.z;
  int jw = blockIdx.y;
  int i  = blockIdx.x * 64 + threadIdx.x;
  int j  = jw * 64 + threadIdx.x;
  double j0 = 0, j1 = 0, j2 = 0, j3 = 0;
  if (j < NPRE) {
    const double* bp = &sbd[((size_t)b * NPRE + j) * 4];
    j0 = bp[0]; j1 = bp[1]; j2 = bp[2]; j3 = bp[3];
  }
  cb[threadIdx.x][0] = j0; cb[threadIdx.x][1] = j1;
  cb[threadIdx.x][2] = j2; cb[threadIdx.x][3] = j3;
  __syncthreads();
  if (i >= NPRE) return;
  const double* bp = &sbd[((size_t)b * NPRE + i) * 4];
  double i0 = bp[0], i1 = bp[1], i2 = bp[2], i3 = bp[3];
  double ai = (i2 - i0) * (i3 - i1);
  unsigned long long mask = 0ull;
#pragma unroll 4
  for (int t = 0; t < 64; ++t) {
    double aj = (cb[t][2] - cb[t][0]) * (cb[t][3] - cb[t][1]);
    double h = fmax(fmin(i2, cb[t][2]) - fmax(i0, cb[t][0]), 0.0);
    double w = fmax(fmin(i3, cb[t][3]) - fmax(i1, cb[t][1]), 0.0);
    double inter = h * w;
    double iou = inter / (ai + aj - inter + 1e-9);
    mask |= ((iou > 0.7) ? 1ull : 0ull) << t;
  }
  M[((size_t)b * ROWPAD + i) * WSTRIDE + jw] = mask;
}

// ---------------- kernel 6: sequential NMS scan (1 wave / image) ----------------
__global__ __launch_bounds__(64) void nms_scan_kernel(
    const double* __restrict__ sbd, const unsigned long long* __restrict__ M,
    float* __restrict__ d_out) {
  int b = blockIdx.x;
  int lane = threadIdx.x;
  for (int k = lane; k < NPOST; k += 64) {
    *(float4*)&d_out[ROIS_OFF + (size_t)(b * NPOST + k) * 4] = make_float4(0, 0, 0, 0);
    d_out[IDX_OFF + b * NPOST + k] = (float)b;
  }
  __syncthreads();

  unsigned long long R = ~0ull;
  if (lane < WORDS) R = 0ull;
  for (int w = 0; w < WORDS; ++w) {
    int j = w * 64 + lane;
    bool inval = true;
    if (j < NPRE) {
      const double* bp = &sbd[((size_t)b * NPRE + j) * 4];
      double h = bp[2] - bp[0], wd = bp[3] - bp[1];
      inval = !(h >= 16.0 && wd >= 16.0);
    }
    unsigned long long bal = __ballot(inval ? 1 : 0);
    if (lane == w) R |= bal;
  }

  int kept = 0;
  while (kept < NPOST) {
    unsigned long long hz = __ballot(((~R) != 0ull) ? 1 : 0);
    if (hz == 0ull) break;
    int w0 = __ffsll(hz) - 1;
    unsigned long long word = __shfl(R, w0);
    int bit = __ffsll(~word) - 1;
    int i = w0 * 64 + bit;
    if (lane < 4)
      d_out[ROIS_OFF + (size_t)(b * NPOST + kept) * 4 + lane] =
          (float)sbd[((size_t)b * NPRE + i) * 4 + lane];
    kept++;
    if (kept >= NPOST) break;
    unsigned long long row = (lane < WORDS)
        ? M[((size_t)b * ROWPAD + i) * WSTRIDE + lane] : 0ull;
    R |= row;
    if (lane == w0) R |= (1ull << bit);
  }
}

// ---------------- launch ----------------
extern "C" void kernel_launch(void* const* d_in, const int* in_sizes, int n_in,
                              void* d_out, int out_size, void* d_ws, size_t ws_size,
                              hipStream_t stream) {
  const float* in     = (const float*)d_in[0];
  const float* conv_w = (const float*)d_in[1];
  const float* conv_b = (const float*)d_in[2];
  const float* bf_w   = (const float*)d_in[3];
  const float* bf_b   = (const float*)d_in[4];
  const float* loc_w  = (const float*)d_in[5];
  const float* loc_b  = (const float*)d_in[6];
  const int*   imh    = (const int*)d_in[7];
  const int*   imw    = (const int*)d_in[8];
  float* out = (float*)d_out;

  char* ws = (char*)d_ws;
  float*  Wt    = (float*)(ws + WS_WT);
  float*  W1t   = (float*)(ws + WS_W1T);
  float*  part0 = (float*)(ws + WS_FEAT);
  unsigned long long* ukey = (unsigned long long*)(ws + WS_SCORE);
  double* boxd  = (double*)(ws + WS_BOXD);
  double* sbd   = (double*)(ws + WS_SBD);
  unsigned long long* M = (unsigned long long*)(ws + WS_M);
  unsigned* cand = (unsigned*)(ws + WS_CAND);
  unsigned* ccnt = (unsigned*)(ws + WS_CNT);
  float*  part1 = (float*)(ws + WS_PART1);
  float*  part2 = (float*)(ws + WS_PART2);
  float*  part3 = (float*)(ws + WS_PART3);
  // head-GEMM partials: reclaim Wt (dead after conv3x3) and M (written later)
  float*  rawp0 = (float*)(ws + WS_WT);
  float*  rawp1 = (float*)(ws + WS_WT + RAWP_SZ);
  float*  rawp2 = (float*)(ws + WS_WT + 2 * RAWP_SZ);
  float*  rawp3 = (float*)(ws + WS_M);

  // conv3x3 K-split factor by available workspace: 4 -> 2 -> 1.
  const int nz = (ws_size >= WS_NEED4) ? 4 : ((ws_size >= WS_NEED2) ? 2 : 1);

  hipLaunchKernelGGL(prep_kernel, dim3((4608 * 512 + 512 * 64 + 255) / 256), dim3(256),
                     0, stream, conv_w, loc_w, bf_w, Wt, W1t);
  hipLaunchKernelGGL(conv3x3_kernel, dim3(79, 8, nz), dim3(256), 0, stream,
                     in, Wt, part0, part1, part2, part3);
  hipLaunchKernelGGL(conv1x1_kernel, dim3(157, 4), dim3(256), 0, stream,
                     part0, part1, part2, part3, nz, conv_b, W1t,
                     rawp0, rawp1, rawp2, rawp3);
  hipLaunchKernelGGL(epilogue_kernel, dim3((BIMG * NLOC + 255) / 256), dim3(256), 0, stream,
                     rawp0, rawp1, rawp2, rawp3, loc_b, bf_b, out, boxd, ukey, imh, imw);
  hipLaunchKernelGGL(thresh_kernel, dim3(4), dim3(1024), 0, stream, ukey, ccnt, cand);
  hipLaunchKernelGGL(rank_kernel, dim3(CAP / 256, 4), dim3(256), 0, stream,
                     ukey, ccnt, cand, boxd, sbd);
  hipLaunchKernelGGL(nmsmask_kernel, dim3(47, 47, 4), dim3(64), 0, stream, sbd, M);
  hipLaunchKernelGGL(nms_scan_kernel, dim3(4), dim3(64), 0, stream, sbd, M, out);
}

// Round 11
// 1324.933 us; speedup vs baseline: 1.4962x; 1.4962x over previous
//
#include <hip/hip_runtime.h>
#include <hip/hip_bf16.h>
#include <math.h>

// ---------------- problem constants ----------------
#define BIMG   4
#define CIN    512
#define MID    512
#define HF     50
#define WF     50
#define PIX    2500          // HF*WF
#define MTOT   10000         // BIMG*PIX
#define ANC    9
#define NLOC   22500         // PIX*ANC
#define NPRE   3000
#define NPOST  300
#define WORDS  47            // ceil(3000/64)
#define ROWPAD 3008
#define WSTRIDE 48           // padded words per NMS row
#define CAP    8192          // candidate capacity per image

// d_out layout (floats): rois, rois_idx, anchors, loc, bf_pred
#define ROIS_OFF 0
#define IDX_OFF  4800
#define ANC_OFF  6000
#define LOC_OFF  96000
#define BF_OFF   456000

// ws layout (byte offsets).
#define WS_WT     0UL                      // 4608*512 f32 = 9,437,184 B; rawp0..2 alias after conv3x3
#define WS_W1T    9437184UL                // 512*64 f32     =   131,072 B
#define WS_FEAT   9568256UL                // 10000*512 f32  = 20,480,000 B (K-split partial 0)
#define WS_SCORE  30048256UL               // 90000 u64 keys =    720,000 B
#define WS_BOXD   30768256UL               // 90000*4 f64    =  2,880,000 B
#define WS_SBD    33648256UL               // 4*3000*4 f64   =    384,000 B
#define WS_M      34032256UL               // 4*3008*48 u64  =  4,620,288 B (rawp3 aliases before nmsmask)
#define WS_CAND   38652544UL               // 4*8192 u32     =    131,072 B
#define WS_CNT    38783616UL               // 4 u32
#define WS_PART1  38786048UL               // partial 1
#define WS_PART2  59266048UL               // partial 2
#define WS_PART3  79746048UL               // partial 3
#define WS_NEED2  59266048UL
#define WS_NEED4  100226048UL
#define RAWP_SZ   2560000UL                // 10000*64 f32

// ---------------- kernel 0: weight prep ----------------
// Wt[(tap*512 + c)*512 + co] = conv_w[co][c][tap]
__global__ __launch_bounds__(256) void prep_kernel(
    const float* __restrict__ conv_w, const float* __restrict__ loc_w,
    const float* __restrict__ bf_w, float* __restrict__ Wt, float* __restrict__ W1t) {
  int o = blockIdx.x * 256 + threadIdx.x;
  if (o < 4608 * 512) {
    int co  = o & 511;
    int k   = o >> 9;          // tap*512 + c
    int c   = k & 511;
    int tap = k >> 9;
    Wt[o] = conv_w[(co * 512 + c) * 9 + tap];
  } else {
    int o2 = o - 4608 * 512;
    if (o2 < 512 * 64) {
      int co = o2 & 63;
      int c  = o2 >> 6;
      float v = 0.0f;
      if (co < 36)      v = loc_w[co * 512 + c];
      else if (co < 54) v = bf_w[(co - 36) * 512 + c];
      W1t[o2] = v;
    }
  }
}

// ---------------- kernel 1: 3x3 conv, K-split partials (R9-exact inner) ----------------
// M=128, 16 cols/wave. B via wave-uniform SCALAR loads (`float bv = br[c]`
// — do NOT vectorize/pack this; R10 showed any type change drops the s_load
// pattern and costs 2x). f32 inner, f64 fold every 2 kb. grid.z splits K.
__device__ __forceinline__ void stage_load(
    int kb, int sg, bool in0, bool in1,
    int y0, int x0, int y1, int x1,
    const float* __restrict__ ib0, const float* __restrict__ ib1, float av[8]) {
  int tap = kb >> 5;
  int c0  = (kb & 31) << 4;
  int t3  = tap / 3;
  int dy  = t3 - 1;
  int dx  = tap - t3 * 3 - 1;
  int iy0 = y0 + dy, ix0 = x0 + dx;
  int iy1 = y1 + dy, ix1 = x1 + dx;
  bool ok0 = in0 && ((unsigned)iy0 < (unsigned)HF) && ((unsigned)ix0 < (unsigned)WF);
  bool ok1 = in1 && ((unsigned)iy1 < (unsigned)HF) && ((unsigned)ix1 < (unsigned)WF);
  int base = (c0 + sg * 4) * PIX;
  int o0 = iy0 * WF + ix0;
  int o1 = iy1 * WF + ix1;
#pragma unroll
  for (int j = 0; j < 4; ++j) {
    av[2 * j]     = ok0 ? ib0[base + j * PIX + o0] : 0.0f;
    av[2 * j + 1] = ok1 ? ib1[base + j * PIX + o1] : 0.0f;
  }
}

__global__ __launch_bounds__(256, 3) void conv3x3_kernel(
    const float* __restrict__ in, const float* __restrict__ Wt,
    float* __restrict__ part0, float* __restrict__ part1,
    float* __restrict__ part2, float* __restrict__ part3) {
  __shared__ float As[2][16][128];
  const int tid = threadIdx.x;
  const int q0 = blockIdx.x * 128;
  const int lane = tid & 63;
  const int wv = tid >> 6;
  const int col0 = __builtin_amdgcn_readfirstlane(blockIdx.y * 64 + wv * 16);
  const int half = 288 / gridDim.z;
  const int kb0 = blockIdx.z * half;
  float* __restrict__ dst = (blockIdx.z == 0) ? part0 :
                            (blockIdx.z == 1) ? part1 :
                            (blockIdx.z == 2) ? part2 : part3;

  // staging geometry: thread handles pixel pair (2*sp, 2*sp+1), kk-quad sg
  const int sg = tid >> 6;
  const int sp = tid & 63;
  int qs0 = q0 + 2 * sp, qs1 = qs0 + 1;
  bool in0 = qs0 < MTOT, in1 = qs1 < MTOT;
  int t0 = in0 ? qs0 : 0, t1 = in1 ? qs1 : 0;
  int b0i = t0 / PIX, r0 = t0 - b0i * PIX, y0 = r0 / WF, x0 = r0 - y0 * WF;
  int b1i = t1 / PIX, r1 = t1 - b1i * PIX, y1 = r1 / WF, x1 = r1 - y1 * WF;
  const float* ib0 = in + (size_t)b0i * (CIN * PIX);
  const float* ib1 = in + (size_t)b1i * (CIN * PIX);

  double acc[2][16];
  float accf[2][16];
#pragma unroll
  for (int p = 0; p < 2; ++p)
#pragma unroll
    for (int c = 0; c < 16; ++c) { acc[p][c] = 0.0; accf[p][c] = 0.0f; }

  // prologue: stage kb0 into buffer 0
  {
    float av[8];
    stage_load(kb0, sg, in0, in1, y0, x0, y1, x1, ib0, ib1, av);
#pragma unroll
    for (int j = 0; j < 4; ++j)
      *(float2*)&As[0][sg * 4 + j][2 * sp] = make_float2(av[2 * j], av[2 * j + 1]);
  }
  __syncthreads();

  for (int kbl = 0; kbl < half; ++kbl) {
    int kb = kb0 + kbl;
    int cur = kbl & 1;
    float av[8];
    bool has_next = (kbl + 1 < half);
    if (has_next)
      stage_load(kb + 1, sg, in0, in1, y0, x0, y1, x1, ib0, ib1, av);

    const float* __restrict__ Bw = Wt + (size_t)(kb * 16) * 512 + col0;
#pragma unroll
    for (int kg = 0; kg < 4; ++kg) {
#pragma unroll
      for (int kq = 0; kq < 4; ++kq) {
        int kk = kg * 4 + kq;
        const float* __restrict__ br = Bw + (size_t)kk * 512;
        float2 a = *(const float2*)&As[cur][kk][2 * lane];
#pragma unroll
        for (int c = 0; c < 16; ++c) {
          float bv = br[c];          // wave-uniform -> s_load (keep scalar!)
          accf[0][c] = fmaf(a.x, bv, accf[0][c]);
          accf[1][c] = fmaf(a.y, bv, accf[1][c]);
        }
      }
    }
    if (kbl & 1) {                 // fold every 2 kb (32-MAC f32 chains)
#pragma unroll
      for (int p = 0; p < 2; ++p)
#pragma unroll
        for (int c = 0; c < 16; ++c) {
          acc[p][c] += (double)accf[p][c];
          accf[p][c] = 0.0f;
        }
    }
    if (has_next) {
      int nxt = cur ^ 1;
#pragma unroll
      for (int j = 0; j < 4; ++j)
        *(float2*)&As[nxt][sg * 4 + j][2 * sp] = make_float2(av[2 * j], av[2 * j + 1]);
    }
    __syncthreads();
  }

#pragma unroll
  for (int p = 0; p < 2; ++p) {
    int q = q0 + 2 * lane + p;
    if (q < MTOT) {
      float o[16];
#pragma unroll
      for (int c = 0; c < 16; ++c) o[c] = (float)acc[p][c];
      float* fp = &dst[(size_t)q * 512 + col0];
#pragma unroll
      for (int g = 0; g < 4; ++g)
        *(float4*)&fp[g * 4] = make_float4(o[g*4], o[g*4+1], o[g*4+2], o[g*4+3]);
    }
  }
}

// ---------------- kernel 2: 1x1 heads, K-split x4 + 64-pixel tile ----------------
// grid (157, 4): block (x,y) computes f32 partial rawp_y[q0..q0+64][64 cols]
// over feat channels [y*128, y*128+128). Staging computes
// relu(conv_b + sum of conv3x3 partials) inline (identical per-element math).
__global__ __launch_bounds__(256) void conv1x1_kernel(
    const float* __restrict__ p0, const float* __restrict__ p1,
    const float* __restrict__ p2, const float* __restrict__ p3, int nz,
    const float* __restrict__ convb, const float* __restrict__ W1t,
    float* __restrict__ rawp0, float* __restrict__ rawp1,
    float* __restrict__ rawp2, float* __restrict__ rawp3) {
  __shared__ float As[16][64];
  const int tid = threadIdx.x;
  const int q0 = blockIdx.x * 64;
  const int by = blockIdx.y;
  const int lane = tid & 63;
  const int wv = tid >> 6;
  const int col0 = __builtin_amdgcn_readfirstlane(wv * 16);   // 4 waves x 16 = 64 cols
  float* __restrict__ rp = (by == 0) ? rawp0 : (by == 1) ? rawp1 :
                           (by == 2) ? rawp2 : rawp3;

  const int sg = tid >> 6;
  const int sp = tid & 63;
  const int qs = q0 + sp;
  const bool okL = qs < MTOT;

  double acc[16];
  float accf[16];
#pragma unroll
  for (int c = 0; c < 16; ++c) { acc[c] = 0.0; accf[c] = 0.0f; }

  for (int kbl = 0; kbl < 8; ++kbl) {
    int kb = by * 8 + kbl;
    int c0 = kb * 16;
    float fv[4] = {0.0f, 0.0f, 0.0f, 0.0f};
    if (okL) {
      const size_t base = (size_t)qs * 512 + c0 + sg * 4;
      double s[4];
      float4 a0 = *(const float4*)&p0[base];
      s[0] = (double)a0.x; s[1] = (double)a0.y; s[2] = (double)a0.z; s[3] = (double)a0.w;
      if (nz > 1) {
        float4 b0 = *(const float4*)&p1[base];
        s[0] += (double)b0.x; s[1] += (double)b0.y; s[2] += (double)b0.z; s[3] += (double)b0.w;
      }
      if (nz > 2) {
        float4 c0v = *(const float4*)&p2[base];
        s[0] += (double)c0v.x; s[1] += (double)c0v.y; s[2] += (double)c0v.z; s[3] += (double)c0v.w;
        float4 d0 = *(const float4*)&p3[base];
        s[0] += (double)d0.x; s[1] += (double)d0.y; s[2] += (double)d0.z; s[3] += (double)d0.w;
      }
      float4 bsv = *(const float4*)&convb[c0 + sg * 4];
      fv[0] = (float)fmax(s[0] + (double)bsv.x, 0.0);
      fv[1] = (float)fmax(s[1] + (double)bsv.y, 0.0);
      fv[2] = (float)fmax(s[2] + (double)bsv.z, 0.0);
      fv[3] = (float)fmax(s[3] + (double)bsv.w, 0.0);
    }
    __syncthreads();
#pragma unroll
    for (int j = 0; j < 4; ++j) As[sg * 4 + j][sp] = fv[j];
    __syncthreads();

    const float* __restrict__ Bw = W1t + (size_t)c0 * 64 + col0;
#pragma unroll
    for (int kk = 0; kk < 16; ++kk) {
      const float* __restrict__ br = Bw + (size_t)kk * 64;
      float a = As[kk][lane];
#pragma unroll
      for (int c = 0; c < 16; ++c)
        accf[c] = fmaf(a, br[c], accf[c]);   // br[c] wave-uniform -> scalar
    }
    if (kbl & 1) {                 // fold every 2 kb (32-MAC chains)
#pragma unroll
      for (int c = 0; c < 16; ++c) {
        acc[c] += (double)accf[c];
        accf[c] = 0.0f;
      }
    }
  }

  int q = q0 + lane;
  if (q < MTOT) {
    float o[16];
#pragma unroll
    for (int c = 0; c < 16; ++c) o[c] = (float)acc[c];
    float* fp = &rp[(size_t)q * 64 + col0];
#pragma unroll
    for (int g = 0; g < 4; ++g)
      *(float4*)&fp[g * 4] = make_float4(o[g*4], o[g*4+1], o[g*4+2], o[g*4+3]);
  }
}

// ---------------- kernel 3: epilogue — sum rawp + head bias (f64), softmax/decode/clip, u64 keys ----------------
__global__ __launch_bounds__(256) void epilogue_kernel(
    const float* __restrict__ r0, const float* __restrict__ r1,
    const float* __restrict__ r2, const float* __restrict__ r3,
    const float* __restrict__ locb, const float* __restrict__ bfb,
    float* __restrict__ d_out, double* __restrict__ boxd,
    unsigned long long* __restrict__ ukey,
    const int* __restrict__ imh, const int* __restrict__ imw) {
  int idx = blockIdx.x * 256 + threadIdx.x;
  if (idx >= BIMG * NLOC) return;
  int b = idx / NLOC;
  int i = idx - b * NLOC;
  int p = i / ANC;
  int a = i - p * ANC;
  int y = p / WF;
  int x = p - y * WF;
  int q = b * PIX + p;
  const size_t rb = (size_t)q * 64;

  // loc: co = a*4 .. a*4+3, bias = locb
  float4 A0 = *(const float4*)&r0[rb + a * 4];
  float4 A1 = *(const float4*)&r1[rb + a * 4];
  float4 A2 = *(const float4*)&r2[rb + a * 4];
  float4 A3 = *(const float4*)&r3[rb + a * 4];
  double l0d = (((double)A0.x + (double)A1.x) + (double)A2.x) + (double)A3.x + (double)locb[a * 4 + 0];
  double l1d = (((double)A0.y + (double)A1.y) + (double)A2.y) + (double)A3.y + (double)locb[a * 4 + 1];
  double l2d = (((double)A0.z + (double)A1.z) + (double)A2.z) + (double)A3.z + (double)locb[a * 4 + 2];
  double l3d = (((double)A0.w + (double)A1.w) + (double)A2.w) + (double)A3.w + (double)locb[a * 4 + 3];
  *(float4*)&d_out[LOC_OFF + (size_t)idx * 4] =
      make_float4((float)l0d, (float)l1d, (float)l2d, (float)l3d);

  // logits: co = 36+2a, 37+2a, bias = bfb
  float2 G0 = *(const float2*)&r0[rb + 36 + a * 2];
  float2 G1 = *(const float2*)&r1[rb + 36 + a * 2];
  float2 G2 = *(const float2*)&r2[rb + 36 + a * 2];
  float2 G3 = *(const float2*)&r3[rb + 36 + a * 2];
  double g0 = (((double)G0.x + (double)G1.x) + (double)G2.x) + (double)G3.x + (double)bfb[a * 2 + 0];
  double g1 = (((double)G0.y + (double)G1.y) + (double)G2.y) + (double)G3.y + (double)bfb[a * 2 + 1];
  double m  = fmax(g0, g1);
  double e0 = exp(g0 - m), e1 = exp(g1 - m);
  double s  = e0 + e1;
  double p0 = e0 / s, p1 = e1 / s;
  *(float2*)&d_out[BF_OFF + (size_t)idx * 2] = make_float2((float)p0, (float)p1);

  // anchor (f64)
  int ridx = a / 3, sidx = a - ridx * 3;
  double ratio = (ridx == 0) ? 0.5 : ((ridx == 1) ? 1.0 : 2.0);
  double scale = (sidx == 0) ? 8.0 : ((sidx == 1) ? 16.0 : 32.0);
  double hs = 16.0 * scale * sqrt(ratio);
  double ws = 16.0 * scale * sqrt(1.0 / ratio);
  double sy = (double)(y * 16), sx = (double)(x * 16);
  double a0 = sy + (8.0 - hs * 0.5);
  double a1 = sx + (8.0 - ws * 0.5);
  double a2 = sy + (8.0 + hs * 0.5);
  double a3 = sx + (8.0 + ws * 0.5);
  if (b == 0) {
    *(float4*)&d_out[ANC_OFF + (size_t)i * 4] =
        make_float4((float)a0, (float)a1, (float)a2, (float)a3);
  }

  // decode + clip (f64)
  double ah = a2 - a0, aw = a3 - a1;
  double acy = a0 + 0.5 * ah, acx = a1 + 0.5 * aw;
  double cy = l0d * ah + acy;
  double cx = l1d * aw + acx;
  double hh = exp(l2d) * ah;
  double ww = exp(l3d) * aw;
  double ihf = (double)imh[0], iwf = (double)imw[0];
  double b0 = fmin(fmax(cy - 0.5 * hh, 0.0), ihf);
  double b1 = fmin(fmax(cx - 0.5 * ww, 0.0), iwf);
  double b2 = fmin(fmax(cy + 0.5 * hh, 0.0), ihf);
  double b3 = fmin(fmax(cx + 0.5 * ww, 0.0), iwf);
  double* bp = &boxd[(size_t)idx * 4];
  bp[0] = b0; bp[1] = b1; bp[2] = b2; bp[3] = b3;

  bool valid = (b2 - b0 >= 16.0) && (b3 - b1 >= 16.0);
  double d = valid ? (g1 - g0) : -INFINITY;
  long long bits = __double_as_longlong(d);
  unsigned long long u = (bits < 0)
      ? ~(unsigned long long)bits
      : ((unsigned long long)bits | 0x8000000000000000ull);
  ukey[idx] = ~u;   // smaller key = better rank
}

// ---------------- kernel 4a: histogram -> threshold bin + candidate compaction ----------------
__global__ __launch_bounds__(1024) void thresh_kernel(
    const unsigned long long* __restrict__ ukey,
    unsigned* __restrict__ ccnt, unsigned* __restrict__ cand) {
  __shared__ unsigned hist[16384];
  __shared__ unsigned csum[1024];
  __shared__ unsigned sT, scnt;
  int b = blockIdx.x;
  int tid = threadIdx.x;
  for (int i = tid; i < 16384; i += 1024) hist[i] = 0;
  if (tid == 0) scnt = 0;
  __syncthreads();
  for (int j = tid; j < NLOC; j += 1024)
    atomicAdd(&hist[(unsigned)(ukey[(size_t)b * NLOC + j] >> 50)], 1u);
  __syncthreads();
  unsigned s = 0;
#pragma unroll
  for (int k = 0; k < 16; ++k) s += hist[tid * 16 + k];
  csum[tid] = s;
  __syncthreads();
  if (tid == 0) {
    unsigned cum = 0;
    int T = 16383;
    for (int c = 0; c < 1024; ++c) {
      if (cum + csum[c] >= NPRE) {
        unsigned cc = cum;
        for (int k = 0; k < 16; ++k) {
          cc += hist[c * 16 + k];
          if (cc >= NPRE) { T = c * 16 + k; break; }
        }
        break;
      }
      cum += csum[c];
    }
    sT = (unsigned)T;
  }
  __syncthreads();
  unsigned T = sT;
  for (int j = tid; j < NLOC; j += 1024) {
    if ((unsigned)(ukey[(size_t)b * NLOC + j] >> 50) <= T) {
      unsigned slot = atomicAdd(&scnt, 1u);
      if (slot < CAP) cand[(size_t)b * CAP + slot] = (unsigned)j;
    }
  }
  __syncthreads();
  if (tid == 0) ccnt[b] = scnt;
}

// ---------------- kernel 4b: exact rank among candidates -> sb ----------------
__global__ __launch_bounds__(256) void rank_kernel(
    const unsigned long long* __restrict__ ukey, const unsigned* __restrict__ ccnt,
    const unsigned* __restrict__ cand, const double* __restrict__ boxd,
    double* __restrict__ sbd) {
  __shared__ unsigned long long kt[256];
  __shared__ unsigned it[256];
  int b = blockIdx.y;
  int C = (int)min(ccnt[b], (unsigned)CAP);
  int s = blockIdx.x * 256 + threadIdx.x;
  bool act = s < C;
  unsigned myi = act ? cand[(size_t)b * CAP + s] : 0xFFFFFFFFu;
  unsigned long long ki = act ? ukey[(size_t)b * NLOC + myi] : ~0ull;
  int cnt = 0;
  int ntile = (C + 255) >> 8;
  for (int t = 0; t < ntile; ++t) {
    int j = t * 256 + threadIdx.x;
    unsigned ji = (j < C) ? cand[(size_t)b * CAP + j] : 0xFFFFFFFFu;
    kt[threadIdx.x] = (j < C) ? ukey[(size_t)b * NLOC + ji] : ~0ull;
    it[threadIdx.x] = ji;
    __syncthreads();
#pragma unroll 8
    for (int jj = 0; jj < 256; ++jj) {
      unsigned long long kj = kt[jj];
      unsigned jidx = it[jj];
      cnt += ((kj < ki) || (kj == ki && jidx < myi)) ? 1 : 0;
    }
    __syncthreads();
  }
  if (act && cnt < NPRE) {
    const double* bx = &boxd[((size_t)b * NLOC + myi) * 4];
    double* dp = &sbd[((size_t)b * NPRE + cnt) * 4];
    dp[0] = bx[0]; dp[1] = bx[1]; dp[2] = bx[2]; dp[3] = bx[3];
  }
}

// ---------------- kernel 5: NMS suppression bitmask matrix (f64 IoU) ----------------
__global__ __launch_bounds__(64) void nmsmask_kernel(
    const double* __restrict__ sbd, unsigned long long* __restrict__ M) {
  __shared__ double cb[64][4];
  int b = blockIdx.z;
  int jw = blockIdx.y;
  int i  = blockIdx.x * 64 + threadIdx.x;
  int j  = jw * 64 + threadIdx.x;
  double j0 = 0, j1 = 0, j2 = 0, j3 = 0;
  if (j < NPRE) {
    const double* bp = &sbd[((size_t)b * NPRE + j) * 4];
    j0 = bp[0]; j1 = bp[1]; j2 = bp[2]; j3 = bp[3];
  }
  cb[threadIdx.x][0] = j0; cb[threadIdx.x][1] = j1;
  cb[threadIdx.x][2] = j2; cb[threadIdx.x][3] = j3;
  __syncthreads();
  if (i >= NPRE) return;
  const double* bp = &sbd[((size_t)b * NPRE + i) * 4];
  double i0 = bp[0], i1 = bp[1], i2 = bp[2], i3 = bp[3];
  double ai = (i2 - i0) * (i3 - i1);
  unsigned long long mask = 0ull;
#pragma unroll 4
  for (int t = 0; t < 64; ++t) {
    double aj = (cb[t][2] - cb[t][0]) * (cb[t][3] - cb[t][1]);
    double h = fmax(fmin(i2, cb[t][2]) - fmax(i0, cb[t][0]), 0.0);
    double w = fmax(fmin(i3, cb[t][3]) - fmax(i1, cb[t][1]), 0.0);
    double inter = h * w;
    double iou = inter / (ai + aj - inter + 1e-9);
    mask |= ((iou > 0.7) ? 1ull : 0ull) << t;
  }
  M[((size_t)b * ROWPAD + i) * WSTRIDE + jw] = mask;
}

// ---------------- kernel 6: sequential NMS scan (1 wave / image) ----------------
__global__ __launch_bounds__(64) void nms_scan_kernel(
    const double* __restrict__ sbd, const unsigned long long* __restrict__ M,
    float* __restrict__ d_out) {
  int b = blockIdx.x;
  int lane = threadIdx.x;
  for (int k = lane; k < NPOST; k += 64) {
    *(float4*)&d_out[ROIS_OFF + (size_t)(b * NPOST + k) * 4] = make_float4(0, 0, 0, 0);
    d_out[IDX_OFF + b * NPOST + k] = (float)b;
  }
  __syncthreads();

  unsigned long long R = ~0ull;
  if (lane < WORDS) R = 0ull;
  for (int w = 0; w < WORDS; ++w) {
    int j = w * 64 + lane;
    bool inval = true;
    if (j < NPRE) {
      const double* bp = &sbd[((size_t)b * NPRE + j) * 4];
      double h = bp[2] - bp[0], wd = bp[3] - bp[1];
      inval = !(h >= 16.0 && wd >= 16.0);
    }
    unsigned long long bal = __ballot(inval ? 1 : 0);
    if (lane == w) R |= bal;
  }

  int kept = 0;
  while (kept < NPOST) {
    unsigned long long hz = __ballot(((~R) != 0ull) ? 1 : 0);
    if (hz == 0ull) break;
    int w0 = __ffsll(hz) - 1;
    unsigned long long word = __shfl(R, w0);
    int bit = __ffsll(~word) - 1;
    int i = w0 * 64 + bit;
    if (lane < 4)
      d_out[ROIS_OFF + (size_t)(b * NPOST + kept) * 4 + lane] =
          (float)sbd[((size_t)b * NPRE + i) * 4 + lane];
    kept++;
    if (kept >= NPOST) break;
    unsigned long long row = (lane < WORDS)
        ? M[((size_t)b * ROWPAD + i) * WSTRIDE + lane] : 0ull;
    R |= row;
    if (lane == w0) R |= (1ull << bit);
  }
}

// ---------------- launch ----------------
extern "C" void kernel_launch(void* const* d_in, const int* in_sizes, int n_in,
                              void* d_out, int out_size, void* d_ws, size_t ws_size,
                              hipStream_t stream) {
  const float* in     = (const float*)d_in[0];
  const float* conv_w = (const float*)d_in[1];
  const float* conv_b = (const float*)d_in[2];
  const float* bf_w   = (const float*)d_in[3];
  const float* bf_b   = (const float*)d_in[4];
  const float* loc_w  = (const float*)d_in[5];
  const float* loc_b  = (const float*)d_in[6];
  const int*   imh    = (const int*)d_in[7];
  const int*   imw    = (const int*)d_in[8];
  float* out = (float*)d_out;

  char* ws = (char*)d_ws;
  float*  Wt    = (float*)(ws + WS_WT);
  float*  W1t   = (float*)(ws + WS_W1T);
  float*  part0 = (float*)(ws + WS_FEAT);
  unsigned long long* ukey = (unsigned long long*)(ws + WS_SCORE);
  double* boxd  = (double*)(ws + WS_BOXD);
  double* sbd   = (double*)(ws + WS_SBD);
  unsigned long long* M = (unsigned long long*)(ws + WS_M);
  unsigned* cand = (unsigned*)(ws + WS_CAND);
  unsigned* ccnt = (unsigned*)(ws + WS_CNT);
  float*  part1 = (float*)(ws + WS_PART1);
  float*  part2 = (float*)(ws + WS_PART2);
  float*  part3 = (float*)(ws + WS_PART3);
  // head-GEMM partials: reclaim Wt (dead after conv3x3) and M (written later)
  float*  rawp0 = (float*)(ws + WS_WT);
  float*  rawp1 = (float*)(ws + WS_WT + RAWP_SZ);
  float*  rawp2 = (float*)(ws + WS_WT + 2 * RAWP_SZ);
  float*  rawp3 = (float*)(ws + WS_M);

  // conv3x3 K-split factor by available workspace: 4 -> 2 -> 1.
  const int nz = (ws_size >= WS_NEED4) ? 4 : ((ws_size >= WS_NEED2) ? 2 : 1);

  hipLaunchKernelGGL(prep_kernel, dim3((4608 * 512 + 512 * 64 + 255) / 256), dim3(256),
                     0, stream, conv_w, loc_w, bf_w, Wt, W1t);
  hipLaunchKernelGGL(conv3x3_kernel, dim3(79, 8, nz), dim3(256), 0, stream,
                     in, Wt, part0, part1, part2, part3);
  hipLaunchKernelGGL(conv1x1_kernel, dim3(157, 4), dim3(256), 0, stream,
                     part0, part1, part2, part3, nz, conv_b, W1t,
                     rawp0, rawp1, rawp2, rawp3);
  hipLaunchKernelGGL(epilogue_kernel, dim3((BIMG * NLOC + 255) / 256), dim3(256), 0, stream,
                     rawp0, rawp1, rawp2, rawp3, loc_b, bf_b, out, boxd, ukey, imh, imw);
  hipLaunchKernelGGL(thresh_kernel, dim3(4), dim3(1024), 0, stream, ukey, ccnt, cand);
  hipLaunchKernelGGL(rank_kernel, dim3(CAP / 256, 4), dim3(256), 0, stream,
                     ukey, ccnt, cand, boxd, sbd);
  hipLaunchKernelGGL(nmsmask_kernel, dim3(47, 47, 4), dim3(64), 0, stream, sbd, M);
  hipLaunchKernelGGL(nms_scan_kernel, dim3(4), dim3(64), 0, stream, sbd, M, out);
}